// Round 1
// 234.028 us; speedup vs baseline: 1.0210x; 1.0210x over previous
//
#include <hip/hip_runtime.h>
#include <hip/hip_bf16.h>
#include <cstdint>

static constexpr int BLK   = 256;
static constexpr int CAP   = 40;    // bucket slots/node; ushort slots -> 80 B
                                    // bucket. Max degree ~35 (Poisson 12.5);
                                    // P(deg>40) ~ 3e-10; overflow -> fixup.
static constexpr int OVMAX = 1024;

typedef __attribute__((ext_vector_type(8))) short bf16x8;
typedef __attribute__((ext_vector_type(4))) float f32x4;

__device__ __forceinline__ float bf16lo(uint32_t u) { return __uint_as_float(u << 16); }
__device__ __forceinline__ float bf16hi(uint32_t u) { return __uint_as_float(u & 0xffff0000u); }
__device__ __forceinline__ unsigned short f2bf(float f) {
    __hip_bfloat16 h = __float2bfloat16(f);
    return *(unsigned short*)&h;
}

// ============================================================ COUNT ========
// blocks [0, gc2):  count + rank, 2 edges/thread (4 atomic-returns in
//   flight/lane). Rank stored as u8 (degree << 255), coalesced (r8 lesson:
//   never scatter on the atomic return; r9 lesson: no bulk BW work beside
//   the atomic fabric stream).
// blocks [gc2, +8): W -> bf16 transposed (tiny; hides under atomic wall).
__global__ __launch_bounds__(BLK) void k_count(
        const int* __restrict__ src, const int* __restrict__ dst,
        int* __restrict__ cnt_f, int* __restrict__ cnt_b,
        unsigned char* __restrict__ rank_f, unsigned char* __restrict__ rank_b,
        int ne,
        const float* __restrict__ Wf, const float* __restrict__ Wb,
        unsigned short* __restrict__ WTf, unsigned short* __restrict__ WTb,
        int gc2) {
    const int bid = blockIdx.x;
    if (bid < gc2) {
        int e0 = bid * (BLK * 2) + threadIdx.x;
        int e1 = e0 + BLK;
        if (e1 < ne) {
            int d0 = dst[e0], s0 = src[e0];
            int d1 = dst[e1], s1 = src[e1];
            int rf0 = atomicAdd(cnt_f + d0, 1);
            int rf1 = atomicAdd(cnt_f + d1, 1);
            int rb0 = atomicAdd(cnt_b + s0, 1);
            int rb1 = atomicAdd(cnt_b + s1, 1);
            rank_f[e0] = (unsigned char)min(rf0, 255);
            rank_f[e1] = (unsigned char)min(rf1, 255);
            rank_b[e0] = (unsigned char)min(rb0, 255);
            rank_b[e1] = (unsigned char)min(rb1, 255);
        } else if (e0 < ne) {
            int d0 = dst[e0], s0 = src[e0];
            rank_f[e0] = (unsigned char)min(atomicAdd(cnt_f + d0, 1), 255);
            rank_b[e0] = (unsigned char)min(atomicAdd(cnt_b + s0, 1), 255);
        }
        return;
    }
    int wb = bid - gc2;                          // 0..7
    for (int idx = wb * 2048 + threadIdx.x; idx < (wb + 1) * 2048; idx += BLK) {
        int c = idx >> 7, k = idx & 127;
        WTf[c * 128 + k] = f2bf(Wf[k * 128 + c]);
        WTb[c * 128 + k] = f2bf(Wb[k * 128 + c]);
    }
}

// ============================================================ PHASE B ======
// Round-11 change: role STRIPING. The fill population (latency-bound 2 B
// scattered stores) and the GEMM population (streaming BW + MFMA) use
// disjoint resources; dispatched sequentially by bid they ran back-to-back
// (phaseB counters: 17% HBM, 5.8% VALU, 2% Mfma — nothing saturated).
// Now: dinv first (tiny, hides under ramp-up), then fill/GEMM Bresenham-
// interleaved so the resident mix always carries both. Fill widened to
// 2 edges/thread (4 scattered stores in flight/lane, all fill co-resident).
__global__ __launch_bounds__(BLK) void k_phaseB(
        const int* __restrict__ src, const int* __restrict__ dst,
        const unsigned char* __restrict__ rank_f,
        const unsigned char* __restrict__ rank_b,
        unsigned short* __restrict__ adj_f, unsigned short* __restrict__ adj_b,
        int* __restrict__ ovcnt, int* __restrict__ ovlist, int ne,
        const float* __restrict__ x,
        const unsigned short* __restrict__ WTf,
        const unsigned short* __restrict__ WTb,
        unsigned short* __restrict__ h_f, unsigned short* __restrict__ h_b,
        const int* __restrict__ cnt_f, const int* __restrict__ cnt_b,
        float* __restrict__ dinv_f, float* __restrict__ dinv_b,
        int n, int gn, int gfill, int gg) {
    const int bid = blockIdx.x;
    if (bid < gn) {
        // ---- dinv = rsqrt(1 + cnt), both directions (tiny; runs first) ----
        int i = bid * BLK + threadIdx.x;
        if (i < n) {
            dinv_f[i] = rsqrtf(1.0f + (float)cnt_f[i]);
            dinv_b[i] = rsqrtf(1.0f + (float)cnt_b[i]);
        }
        return;
    }
    const int  sb = bid - gn;
    const long T  = (long)gfill + gg;
    const long p0 = (long)sb * gfill / T;
    const long p1 = (long)(sb + 1) * gfill / T;
    if (p1 > p0) {
        // ---- bucket fill: atomic-free 2 B scattered stores, 2 edges/thread
        const int fb = (int)p0;
        int e0 = fb * (BLK * 2) + threadIdx.x;
        int e1 = e0 + BLK;
        if (e1 < ne) {
            int s0 = src[e0], d0 = dst[e0];
            int s1 = src[e1], d1 = dst[e1];
            int rf0 = rank_f[e0], rf1 = rank_f[e1];
            int rb0 = rank_b[e0], rb1 = rank_b[e1];
            if (rf0 < CAP) adj_f[d0 * CAP + rf0] = (unsigned short)s0;
            else { int q = atomicAdd(ovcnt, 1); if (q < OVMAX) ovlist[q] = e0 * 2 + 0; }
            if (rb0 < CAP) adj_b[s0 * CAP + rb0] = (unsigned short)d0;
            else { int q = atomicAdd(ovcnt, 1); if (q < OVMAX) ovlist[q] = e0 * 2 + 1; }
            if (rf1 < CAP) adj_f[d1 * CAP + rf1] = (unsigned short)s1;
            else { int q = atomicAdd(ovcnt, 1); if (q < OVMAX) ovlist[q] = e1 * 2 + 0; }
            if (rb1 < CAP) adj_b[s1 * CAP + rb1] = (unsigned short)d1;
            else { int q = atomicAdd(ovcnt, 1); if (q < OVMAX) ovlist[q] = e1 * 2 + 1; }
        } else if (e0 < ne) {
            int s = src[e0], d = dst[e0];
            int rf = rank_f[e0];
            if (rf < CAP) adj_f[d * CAP + rf] = (unsigned short)s;
            else { int q = atomicAdd(ovcnt, 1); if (q < OVMAX) ovlist[q] = e0 * 2 + 0; }
            int rb = rank_b[e0];
            if (rb < CAP) adj_b[s * CAP + rb] = (unsigned short)d;
            else { int q = atomicAdd(ovcnt, 1); if (q < OVMAX) ovlist[q] = e0 * 2 + 1; }
        }
        return;
    }
    // ---- MFMA GEMM h = bf16(x @ W) unscaled, from f32 x ----
    {
        const int gb   = (int)(sb - p0);         // GEMM block index 0..gg-1
        const int wave = threadIdx.x >> 6;
        const int lane = threadIdx.x & 63;
        const int conv = wave >> 1;
        const int n0   = (wave & 1) * 64;
        const int m0   = gb * 16;
        const int q    = lane >> 4;
        const int t16  = lane & 15;

        const unsigned short* __restrict__ WT = conv ? WTb : WTf;
        unsigned short* __restrict__ h        = conv ? h_b : h_f;

        int arow = m0 + t16; if (arow >= n) arow = n - 1;
        const float* __restrict__ xr = x + (size_t)arow * 128;
        bf16x8 a[4];
#pragma unroll
        for (int s = 0; s < 4; ++s) {
            float4 p0v = *(const float4*)(xr + s * 32 + q * 8);
            float4 p1v = *(const float4*)(xr + s * 32 + q * 8 + 4);
            bf16x8 v;
            v[0] = (short)f2bf(p0v.x); v[1] = (short)f2bf(p0v.y);
            v[2] = (short)f2bf(p0v.z); v[3] = (short)f2bf(p0v.w);
            v[4] = (short)f2bf(p1v.x); v[5] = (short)f2bf(p1v.y);
            v[6] = (short)f2bf(p1v.z); v[7] = (short)f2bf(p1v.w);
            a[s] = v;
        }
#pragma unroll
        for (int t = 0; t < 4; ++t) {
            const unsigned short* wrow = WT + (size_t)(n0 + t * 16 + t16) * 128;
            f32x4 c = {0.f, 0.f, 0.f, 0.f};
#pragma unroll
            for (int s = 0; s < 4; ++s) {
                bf16x8 b = *(const bf16x8*)(wrow + s * 32 + q * 8);
                c = __builtin_amdgcn_mfma_f32_16x16x32_bf16(a[s], b, c, 0, 0, 0);
            }
#pragma unroll
            for (int r = 0; r < 4; ++r) {
                int row = m0 + q * 4 + r;
                if (row < n)
                    h[(size_t)row * 128 + n0 + t * 16 + t16] = f2bf(c[r]);
            }
        }
    }
}

// ============================================================ GATHER =======
// blocks [0, gnode):       wave per node; lane owns one bf16x2 dword.
//   Unified direction loop (round-10 win): both convs' neighbors in one
//   lane-list; h_b addressed as h_f + nwords; one 8-wide MLP loop.
// blocks [gnode, gnode+8): exact recompute of CAP-overflowed rows (no-op
//   when *ovcnt == 0, the expected case).
__global__ __launch_bounds__(BLK) void k_gatherX(
        const int* __restrict__ cnt_f, const unsigned short* __restrict__ adj_f,
        const int* __restrict__ cnt_b, const unsigned short* __restrict__ adj_b,
        const float* __restrict__ dinv_f, const float* __restrict__ dinv_b,
        const uint32_t* __restrict__ hf, const uint32_t* __restrict__ hb,
        const float* __restrict__ bf, const float* __restrict__ bb,
        float* __restrict__ out, int n, int gnode, int nwords,
        const int* __restrict__ ovcnt, const int* __restrict__ ovlist,
        const int* __restrict__ src, const int* __restrict__ dst, int ne) {
    const int bid = blockIdx.x;
    if (bid < gnode) {
        const int wave = threadIdx.x >> 6;
        const int lane = threadIdx.x & 63;
        const int node = bid * 4 + wave;
        if (node >= n) return;

        int cf = cnt_f[node], cb = cnt_b[node];
        if (cf > CAP || cb > CAP) return;          // fixup owns this row

        float dvsf = dinv_f[node], dvsb = dinv_b[node];
        uint32_t uf = hf[(size_t)node * 64 + lane];
        uint32_t ub = hf[(size_t)(nwords + node * 64 + lane)];
        float acc0 = dvsf * dvsf * bf16lo(uf) + dvsb * dvsb * bf16lo(ub);
        float acc1 = dvsf * dvsf * bf16hi(uf) + dvsb * dvsb * bf16hi(ub);

        const int mt = cf + cb;
        if (mt <= 64) {
            int ofs = 0; float sc = 0.f;
            if (lane < cf) {
                int nb = adj_f[node * CAP + lane];
                ofs = nb * 64;
                sc  = dvsf * dinv_f[nb];
            } else if (lane < mt) {
                int nb = adj_b[node * CAP + (lane - cf)];
                ofs = nwords + nb * 64;
                sc  = dvsb * dinv_b[nb];
            }
            int j = 0;
            for (; j + 8 <= mt; j += 8) {
                int   o0 = __shfl(ofs, j + 0), o1 = __shfl(ofs, j + 1);
                int   o2 = __shfl(ofs, j + 2), o3 = __shfl(ofs, j + 3);
                int   o4 = __shfl(ofs, j + 4), o5 = __shfl(ofs, j + 5);
                int   o6 = __shfl(ofs, j + 6), o7 = __shfl(ofs, j + 7);
                float s0 = __shfl(sc, j + 0), s1 = __shfl(sc, j + 1);
                float s2 = __shfl(sc, j + 2), s3 = __shfl(sc, j + 3);
                float s4 = __shfl(sc, j + 4), s5 = __shfl(sc, j + 5);
                float s6 = __shfl(sc, j + 6), s7 = __shfl(sc, j + 7);
                uint32_t u0 = hf[(size_t)(o0 + lane)];
                uint32_t u1 = hf[(size_t)(o1 + lane)];
                uint32_t u2 = hf[(size_t)(o2 + lane)];
                uint32_t u3 = hf[(size_t)(o3 + lane)];
                uint32_t u4 = hf[(size_t)(o4 + lane)];
                uint32_t u5 = hf[(size_t)(o5 + lane)];
                uint32_t u6 = hf[(size_t)(o6 + lane)];
                uint32_t u7 = hf[(size_t)(o7 + lane)];
                acc0 = fmaf(s0, bf16lo(u0), acc0); acc1 = fmaf(s0, bf16hi(u0), acc1);
                acc0 = fmaf(s1, bf16lo(u1), acc0); acc1 = fmaf(s1, bf16hi(u1), acc1);
                acc0 = fmaf(s2, bf16lo(u2), acc0); acc1 = fmaf(s2, bf16hi(u2), acc1);
                acc0 = fmaf(s3, bf16lo(u3), acc0); acc1 = fmaf(s3, bf16hi(u3), acc1);
                acc0 = fmaf(s4, bf16lo(u4), acc0); acc1 = fmaf(s4, bf16hi(u4), acc1);
                acc0 = fmaf(s5, bf16lo(u5), acc0); acc1 = fmaf(s5, bf16hi(u5), acc1);
                acc0 = fmaf(s6, bf16lo(u6), acc0); acc1 = fmaf(s6, bf16hi(u6), acc1);
                acc0 = fmaf(s7, bf16lo(u7), acc0); acc1 = fmaf(s7, bf16hi(u7), acc1);
            }
            for (; j + 4 <= mt; j += 4) {
                int   o0 = __shfl(ofs, j + 0), o1 = __shfl(ofs, j + 1);
                int   o2 = __shfl(ofs, j + 2), o3 = __shfl(ofs, j + 3);
                float s0 = __shfl(sc, j + 0), s1 = __shfl(sc, j + 1);
                float s2 = __shfl(sc, j + 2), s3 = __shfl(sc, j + 3);
                uint32_t u0 = hf[(size_t)(o0 + lane)];
                uint32_t u1 = hf[(size_t)(o1 + lane)];
                uint32_t u2 = hf[(size_t)(o2 + lane)];
                uint32_t u3 = hf[(size_t)(o3 + lane)];
                acc0 = fmaf(s0, bf16lo(u0), acc0); acc1 = fmaf(s0, bf16hi(u0), acc1);
                acc0 = fmaf(s1, bf16lo(u1), acc0); acc1 = fmaf(s1, bf16hi(u1), acc1);
                acc0 = fmaf(s2, bf16lo(u2), acc0); acc1 = fmaf(s2, bf16hi(u2), acc1);
                acc0 = fmaf(s3, bf16lo(u3), acc0); acc1 = fmaf(s3, bf16hi(u3), acc1);
            }
            for (; j < mt; ++j) {
                int oj = __shfl(ofs, j); float sj = __shfl(sc, j);
                uint32_t uj = hf[(size_t)(oj + lane)];
                acc0 = fmaf(sj, bf16lo(uj), acc0); acc1 = fmaf(sj, bf16hi(uj), acc1);
            }
        } else {
            // ultra-rare exact fallback (cf+cb > 64)
            for (int j = 0; j < cf; ++j) {
                int nb = adj_f[node * CAP + j];
                float dj = dvsf * dinv_f[nb];
                uint32_t u = hf[(size_t)nb * 64 + lane];
                acc0 = fmaf(dj, bf16lo(u), acc0); acc1 = fmaf(dj, bf16hi(u), acc1);
            }
            for (int j = 0; j < cb; ++j) {
                int nb = adj_b[node * CAP + j];
                float dj = dvsb * dinv_b[nb];
                uint32_t u = hf[(size_t)(nwords + nb * 64 + lane)];
                acc0 = fmaf(dj, bf16lo(u), acc0); acc1 = fmaf(dj, bf16hi(u), acc1);
            }
        }

        const float2 biasf = ((const float2*)bf)[lane];
        const float2 biasb = ((const float2*)bb)[lane];
        float v0 = acc0 + biasf.x + biasb.x;
        float v1 = acc1 + biasf.y + biasb.y;
        ((float2*)out)[(size_t)node * 64 + lane] =
            make_float2(fmaxf(v0, 0.0f), fmaxf(v1, 0.0f));
        return;
    }

    // ---- fixup blocks: exact recompute of overflowed rows ----
    int nov = *ovcnt; if (nov > OVMAX) nov = OVMAX;
    if (nov == 0) return;
    __shared__ int lst[4096];
    __shared__ int lcnt;
    const int tid = threadIdx.x;
    for (int i = bid - gnode; i < nov; i += 8) {
        int code = ovlist[i];
        int e = code >> 1, dir = code & 1;
        int node = dir ? src[e] : dst[e];
        float acc0 = 0.f, acc1 = 0.f;
        for (int d2 = 0; d2 < 2; ++d2) {
            const int* key = d2 ? src : dst;
            const int* val = d2 ? dst : src;
            const float* dinv = d2 ? dinv_b : dinv_f;
            int base = d2 ? nwords : 0;
            float dvs = dinv[node];
            float s0 = 0.f, s1 = 0.f;
            if (tid < 64) {
                uint32_t u = hf[(size_t)(base + node * 64 + tid)];
                s0 = dvs * bf16lo(u); s1 = dvs * bf16hi(u);
            }
            for (int start = 0; start < ne; start += 4096) {
                if (tid == 0) lcnt = 0;
                __syncthreads();
                int end = min(start + 4096, ne);
                for (int e2 = start + tid; e2 < end; e2 += BLK)
                    if (key[e2] == node) { int q = atomicAdd(&lcnt, 1); lst[q] = val[e2]; }
                __syncthreads();
                int mm = lcnt;
                if (tid < 64) {
                    for (int j = 0; j < mm; ++j) {
                        int nb = lst[j];
                        float dv = dinv[nb];
                        uint32_t u = hf[(size_t)(base + nb * 64 + tid)];
                        s0 = fmaf(dv, bf16lo(u), s0);
                        s1 = fmaf(dv, bf16hi(u), s1);
                    }
                }
                __syncthreads();
            }
            if (tid < 64) { acc0 += dvs * s0; acc1 += dvs * s1; }
        }
        if (tid < 64) {
            float2 biasf = ((const float2*)bf)[tid];
            float2 biasb = ((const float2*)bb)[tid];
            float v0 = acc0 + biasf.x + biasb.x;
            float v1 = acc1 + biasf.y + biasb.y;
            ((float2*)out)[(size_t)node * 64 + tid] =
                make_float2(fmaxf(v0, 0.0f), fmaxf(v1, 0.0f));
        }
        __syncthreads();
    }
}

// ============================================================ launcher =====
extern "C" void kernel_launch(void* const* d_in, const int* in_sizes, int n_in,
                              void* d_out, int out_size, void* d_ws, size_t ws_size,
                              hipStream_t stream) {
    const float* x  = (const float*)d_in[0];
    const int*   ei = (const int*)d_in[1];
    const float* Wf = (const float*)d_in[2];
    const float* bf = (const float*)d_in[3];
    const float* Wb = (const float*)d_in[4];
    const float* bb = (const float*)d_in[5];

    const int n  = in_sizes[0] / 128;   // 50000
    const int ne = in_sizes[1] / 2;     // 625000
    const int* src = ei;
    const int* dst = ei + ne;
    float* out = (float*)d_out;

    // workspace layout (16B-aligned; n, ne multiples of 4)
    // h_f and h_b contiguous (gather addresses h_b as h_f + nwords dwords)
    char* w = (char*)d_ws;
    unsigned short* h_f = (unsigned short*)w;   w += (size_t)n * 128 * 2;
    unsigned short* h_b = (unsigned short*)w;   w += (size_t)n * 128 * 2;
    unsigned short* adj_f = (unsigned short*)w; w += (size_t)n * CAP * 2;  // 4 MB
    unsigned short* adj_b = (unsigned short*)w; w += (size_t)n * CAP * 2;
    unsigned char* rank_f = (unsigned char*)w;  w += (size_t)ne;           // 0.6 MB
    unsigned char* rank_b = (unsigned char*)w;  w += (size_t)ne;
    float* dinv_f = (float*)w;                  w += (size_t)n * 4;
    float* dinv_b = (float*)w;                  w += (size_t)n * 4;
    unsigned short* WTf = (unsigned short*)w;   w += 128 * 128 * 2;
    unsigned short* WTb = (unsigned short*)w;   w += 128 * 128 * 2;
    int* cnt_f = (int*)w;                       w += (size_t)n * 4;   // ---- zero
    int* cnt_b = (int*)w;                       w += (size_t)n * 4;   //  region
    int* ovcnt = (int*)w;                       w += 8 * 4;           // ----
    int* ovlist = (int*)w;                      w += OVMAX * 4;

    const int gc2   = (ne + BLK * 2 - 1) / (BLK * 2);   // 1221 count blocks
    const int gfill = (ne + BLK * 2 - 1) / (BLK * 2);   // 1221 fill blocks (2 e/t)
    const int gg    = (n + 15) / 16;                    // 3125 gemm blocks
    const int gn    = (n + BLK - 1) / BLK;              // 196 dinv blocks
    const int gnode = (n + 3) / 4;                      // 12500

    hipMemsetAsync(cnt_f, 0, (size_t)(2 * n + 8) * 4, stream);

    k_count <<<gc2 + 8, BLK, 0, stream>>>(src, dst, cnt_f, cnt_b,
                                          rank_f, rank_b, ne,
                                          Wf, Wb, WTf, WTb, gc2);

    k_phaseB<<<gn + gfill + gg, BLK, 0, stream>>>(src, dst, rank_f, rank_b,
                                                  adj_f, adj_b, ovcnt, ovlist, ne,
                                                  x, WTf, WTb, h_f, h_b,
                                                  cnt_f, cnt_b, dinv_f, dinv_b,
                                                  n, gn, gfill, gg);

    k_gatherX<<<gnode + 8, BLK, 0, stream>>>(cnt_f, adj_f, cnt_b, adj_b,
                                             dinv_f, dinv_b,
                                             (const uint32_t*)h_f,
                                             (const uint32_t*)h_b,
                                             bf, bb, out, n, gnode, n * 64,
                                             ovcnt, ovlist, src, dst, ne);
}

// Round 2
// 191.618 us; speedup vs baseline: 1.2469x; 1.2213x over previous
//
#include <hip/hip_runtime.h>
#include <hip/hip_bf16.h>
#include <cstdint>

static constexpr int BLK      = 256;
static constexpr int CAP      = 40;     // adj slots/node (80 B). P(deg>40)~3e-10.
static constexpr int BINSHIFT = 8;      // 256 nodes per bin
static constexpr int BINNODES = 1 << BINSHIFT;
static constexpr int BINCAP   = BINNODES * CAP / 2;  // 5120 pairs; 5120*4B == 256*CAP*2B
                                        // (pair segment overlays adj segment exactly)
static constexpr int EPB      = 2048;   // edges per binning block (8/thread)
static constexpr int OVMAX    = 1024;

typedef __attribute__((ext_vector_type(8))) short bf16x8;
typedef __attribute__((ext_vector_type(4))) float f32x4;

__device__ __forceinline__ float bf16lo(uint32_t u) { return __uint_as_float(u << 16); }
__device__ __forceinline__ float bf16hi(uint32_t u) { return __uint_as_float(u & 0xffff0000u); }
__device__ __forceinline__ unsigned short f2bf(float f) {
    __hip_bfloat16 h = __float2bfloat16(f);
    return *(unsigned short*)&h;
}

// ============================================================ PREP =========
// blocks 0..7: W -> bf16 transposed. block 8: zero bin counters + ovcnt.
// (Replaces the old k_count 1.25M-atomic wall AND the cnt memset.)
__global__ __launch_bounds__(BLK) void k_prep(
        const float* __restrict__ Wf, const float* __restrict__ Wb,
        unsigned short* __restrict__ WTf, unsigned short* __restrict__ WTb,
        int* __restrict__ gcnt, int gcnt_words) {
    const int bid = blockIdx.x;
    if (bid < 8) {
        for (int idx = bid * 2048 + threadIdx.x; idx < (bid + 1) * 2048; idx += BLK) {
            int c = idx >> 7, k = idx & 127;
            WTf[c * 128 + k] = f2bf(Wf[k * 128 + c]);
            WTb[c * 128 + k] = f2bf(Wb[k * 128 + c]);
        }
        return;
    }
    for (int i = threadIdx.x; i < gcnt_words; i += BLK) gcnt[i] = 0;
}

// ============================================================ BIN + GEMM ===
// blocks [0, gbin):      counting-sort pass 1. LDS histogram (196 bins) ->
//   one global atomicAdd per (block,bin) to reserve a segment slice ->
//   append (node16|val16) pairs. Appends are cursor-sequential per bin:
//   active write set ~392 hot lines (r11 lesson: random 2B RMW scatter
//   churned 37-52 MB of L2 writebacks; appends don't).
// blocks [gbin, +gg):    MFMA GEMM h = bf16(x @ W), unchanged.
__global__ __launch_bounds__(BLK) void k_bin_gemm(
        const int* __restrict__ src, const int* __restrict__ dst, int ne,
        uint32_t* __restrict__ pair_f, uint32_t* __restrict__ pair_b,
        int* __restrict__ gcnt_f, int* __restrict__ gcnt_b,
        int* __restrict__ ovcnt, int* __restrict__ ovlist,
        const float* __restrict__ x,
        const unsigned short* __restrict__ WTf,
        const unsigned short* __restrict__ WTb,
        unsigned short* __restrict__ h_f, unsigned short* __restrict__ h_b,
        int n, int nbins, int gbin) {
    const int bid = blockIdx.x;
    if (bid < gbin) {
        __shared__ int curf[BINNODES], curb[BINNODES];   // histo, then cursors
        const int tid = threadIdx.x;
        curf[tid] = 0; curb[tid] = 0;                    // BLK == BINNODES
        __syncthreads();

        int s[8], d[8];
        const int e0 = bid * EPB + tid;
#pragma unroll
        for (int k = 0; k < 8; ++k) {
            int e = e0 + k * BLK;
            bool v = e < ne;
            s[k] = v ? src[e] : -1;
            d[k] = v ? dst[e] : -1;
            if (v) {
                atomicAdd(&curf[d[k] >> BINSHIFT], 1);
                atomicAdd(&curb[s[k] >> BINSHIFT], 1);
            }
        }
        __syncthreads();
        // reserve global segment slices; cursor := global base
        int cf = curf[tid], cb = curb[tid];   // own slot: no race with own write
        if (tid < nbins) {
            curf[tid] = cf ? atomicAdd(&gcnt_f[tid], cf) : 0;
            curb[tid] = cb ? atomicAdd(&gcnt_b[tid], cb) : 0;
        }
        __syncthreads();
#pragma unroll
        for (int k = 0; k < 8; ++k) {
            if (s[k] >= 0) {
                int bf = d[k] >> BINSHIFT;
                int rf = atomicAdd(&curf[bf], 1);
                if (rf < BINCAP)
                    pair_f[(size_t)bf * BINCAP + rf] =
                        ((uint32_t)d[k] << 16) | (uint32_t)s[k];
                else { int q = atomicAdd(ovcnt, 1); if (q < OVMAX) ovlist[q] = (d[k] << 1) | 0; }
                int bb = s[k] >> BINSHIFT;
                int rb = atomicAdd(&curb[bb], 1);
                if (rb < BINCAP)
                    pair_b[(size_t)bb * BINCAP + rb] =
                        ((uint32_t)s[k] << 16) | (uint32_t)d[k];
                else { int q = atomicAdd(ovcnt, 1); if (q < OVMAX) ovlist[q] = (s[k] << 1) | 1; }
            }
        }
        return;
    }
    // ---- MFMA GEMM h = bf16(x @ W) unscaled, from f32 x ----
    {
        const int gb   = bid - gbin;
        const int wave = threadIdx.x >> 6;
        const int lane = threadIdx.x & 63;
        const int conv = wave >> 1;
        const int n0   = (wave & 1) * 64;
        const int m0   = gb * 16;
        const int q    = lane >> 4;
        const int t16  = lane & 15;

        const unsigned short* __restrict__ WT = conv ? WTb : WTf;
        unsigned short* __restrict__ h        = conv ? h_b : h_f;

        int arow = m0 + t16; if (arow >= n) arow = n - 1;
        const float* __restrict__ xr = x + (size_t)arow * 128;
        bf16x8 a[4];
#pragma unroll
        for (int s2 = 0; s2 < 4; ++s2) {
            float4 p0v = *(const float4*)(xr + s2 * 32 + q * 8);
            float4 p1v = *(const float4*)(xr + s2 * 32 + q * 8 + 4);
            bf16x8 v;
            v[0] = (short)f2bf(p0v.x); v[1] = (short)f2bf(p0v.y);
            v[2] = (short)f2bf(p0v.z); v[3] = (short)f2bf(p0v.w);
            v[4] = (short)f2bf(p1v.x); v[5] = (short)f2bf(p1v.y);
            v[6] = (short)f2bf(p1v.z); v[7] = (short)f2bf(p1v.w);
            a[s2] = v;
        }
#pragma unroll
        for (int t = 0; t < 4; ++t) {
            const unsigned short* wrow = WT + (size_t)(n0 + t * 16 + t16) * 128;
            f32x4 c = {0.f, 0.f, 0.f, 0.f};
#pragma unroll
            for (int s2 = 0; s2 < 4; ++s2) {
                bf16x8 b = *(const bf16x8*)(wrow + s2 * 32 + q * 8);
                c = __builtin_amdgcn_mfma_f32_16x16x32_bf16(a[s2], b, c, 0, 0, 0);
            }
#pragma unroll
            for (int r = 0; r < 4; ++r) {
                int row = m0 + q * 4 + r;
                if (row < n)
                    h[(size_t)row * 128 + n0 + t * 16 + t16] = f2bf(c[r]);
            }
        }
    }
}

// ============================================================ BUILD ========
// counting-sort pass 2: one block per (bin,dir). Coalesced read of the
// bin's pair segment -> LDS-atomic rank -> 20 KB LDS bucket image ->
// coalesced full-line dump (overwrites the pair segment in place; the
// segment layouts are byte-identical). cnt + dinv computed here (exact).
__global__ __launch_bounds__(BLK) void k_build(
        const uint32_t* __restrict__ pair_f, const uint32_t* __restrict__ pair_b,
        const int* __restrict__ gcnt_f, const int* __restrict__ gcnt_b,
        unsigned short* __restrict__ adj_f, unsigned short* __restrict__ adj_b,
        int* __restrict__ cnt_f, int* __restrict__ cnt_b,
        float* __restrict__ dinv_f, float* __restrict__ dinv_b,
        int* __restrict__ ovcnt, int* __restrict__ ovlist,
        int n, int nbins) {
    const int tid = threadIdx.x;
    const int b   = blockIdx.x;
    const int dir = b >= nbins ? 1 : 0;
    const int bin = b - dir * nbins;

    const uint32_t* __restrict__ pairs = dir ? pair_b : pair_f;
    unsigned short* __restrict__ adj   = dir ? adj_b : adj_f;
    int*   cnt  = dir ? cnt_b  : cnt_f;
    float* dinv = dir ? dinv_b : dinv_f;
    int count = dir ? gcnt_b[bin] : gcnt_f[bin];
    if (count > BINCAP) count = BINCAP;

    __shared__ unsigned short buck[BINNODES * CAP];   // 20 KB
    __shared__ int lcnt[BINNODES];                    // 1 KB
    lcnt[tid] = 0;
    __syncthreads();

    const uint32_t* pb = pairs + (size_t)bin * BINCAP;
    for (int i = tid; i < count; i += BLK) {
        uint32_t p = pb[i];
        int l = (p >> 16) & (BINNODES - 1);
        int r = atomicAdd(&lcnt[l], 1);
        if (r < CAP) buck[l * CAP + r] = (unsigned short)(p & 0xffffu);
        else {
            int q = atomicAdd(ovcnt, 1);
            if (q < OVMAX) ovlist[q] = ((((bin << BINSHIFT) + l) << 1) | dir);
        }
    }
    __syncthreads();

    const int node0 = bin << BINSHIFT;
    const int node  = node0 + tid;
    if (node < n) {
        int c = lcnt[tid];
        cnt[node]  = c;
        dinv[node] = rsqrtf(1.0f + (float)c);
    }
    uint32_t* adjseg = (uint32_t*)(adj + (size_t)node0 * CAP);
    const uint32_t* b32 = (const uint32_t*)buck;
    for (int i = tid; i < BINCAP; i += BLK) adjseg[i] = b32[i];
}

// ============================================================ GATHER =======
// blocks [0, gnode):       wave per node; lane owns one bf16x2 dword.
// blocks [gnode, gnode+8): exact recompute of CAP-overflowed rows (no-op
//   when *ovcnt == 0, the expected case). ovlist encodes (node<<1)|dir.
__global__ __launch_bounds__(BLK) void k_gatherX(
        const int* __restrict__ cnt_f, const unsigned short* __restrict__ adj_f,
        const int* __restrict__ cnt_b, const unsigned short* __restrict__ adj_b,
        const float* __restrict__ dinv_f, const float* __restrict__ dinv_b,
        const uint32_t* __restrict__ hf, const uint32_t* __restrict__ hb,
        const float* __restrict__ bf, const float* __restrict__ bb,
        float* __restrict__ out, int n, int gnode, int nwords,
        const int* __restrict__ ovcnt, const int* __restrict__ ovlist,
        const int* __restrict__ src, const int* __restrict__ dst, int ne) {
    const int bid = blockIdx.x;
    if (bid < gnode) {
        const int wave = threadIdx.x >> 6;
        const int lane = threadIdx.x & 63;
        const int node = bid * 4 + wave;
        if (node >= n) return;

        int cf = cnt_f[node], cb = cnt_b[node];
        if (cf > CAP || cb > CAP) return;          // fixup owns this row

        float dvsf = dinv_f[node], dvsb = dinv_b[node];
        uint32_t uf = hf[(size_t)node * 64 + lane];
        uint32_t ub = hf[(size_t)(nwords + node * 64 + lane)];
        float acc0 = dvsf * dvsf * bf16lo(uf) + dvsb * dvsb * bf16lo(ub);
        float acc1 = dvsf * dvsf * bf16hi(uf) + dvsb * dvsb * bf16hi(ub);

        const int mt = cf + cb;
        if (mt <= 64) {
            int ofs = 0; float sc = 0.f;
            if (lane < cf) {
                int nb = adj_f[node * CAP + lane];
                ofs = nb * 64;
                sc  = dvsf * dinv_f[nb];
            } else if (lane < mt) {
                int nb = adj_b[node * CAP + (lane - cf)];
                ofs = nwords + nb * 64;
                sc  = dvsb * dinv_b[nb];
            }
            int j = 0;
            for (; j + 8 <= mt; j += 8) {
                int   o0 = __shfl(ofs, j + 0), o1 = __shfl(ofs, j + 1);
                int   o2 = __shfl(ofs, j + 2), o3 = __shfl(ofs, j + 3);
                int   o4 = __shfl(ofs, j + 4), o5 = __shfl(ofs, j + 5);
                int   o6 = __shfl(ofs, j + 6), o7 = __shfl(ofs, j + 7);
                float s0 = __shfl(sc, j + 0), s1 = __shfl(sc, j + 1);
                float s2 = __shfl(sc, j + 2), s3 = __shfl(sc, j + 3);
                float s4 = __shfl(sc, j + 4), s5 = __shfl(sc, j + 5);
                float s6 = __shfl(sc, j + 6), s7 = __shfl(sc, j + 7);
                uint32_t u0 = hf[(size_t)(o0 + lane)];
                uint32_t u1 = hf[(size_t)(o1 + lane)];
                uint32_t u2 = hf[(size_t)(o2 + lane)];
                uint32_t u3 = hf[(size_t)(o3 + lane)];
                uint32_t u4 = hf[(size_t)(o4 + lane)];
                uint32_t u5 = hf[(size_t)(o5 + lane)];
                uint32_t u6 = hf[(size_t)(o6 + lane)];
                uint32_t u7 = hf[(size_t)(o7 + lane)];
                acc0 = fmaf(s0, bf16lo(u0), acc0); acc1 = fmaf(s0, bf16hi(u0), acc1);
                acc0 = fmaf(s1, bf16lo(u1), acc0); acc1 = fmaf(s1, bf16hi(u1), acc1);
                acc0 = fmaf(s2, bf16lo(u2), acc0); acc1 = fmaf(s2, bf16hi(u2), acc1);
                acc0 = fmaf(s3, bf16lo(u3), acc0); acc1 = fmaf(s3, bf16hi(u3), acc1);
                acc0 = fmaf(s4, bf16lo(u4), acc0); acc1 = fmaf(s4, bf16hi(u4), acc1);
                acc0 = fmaf(s5, bf16lo(u5), acc0); acc1 = fmaf(s5, bf16hi(u5), acc1);
                acc0 = fmaf(s6, bf16lo(u6), acc0); acc1 = fmaf(s6, bf16hi(u6), acc1);
                acc0 = fmaf(s7, bf16lo(u7), acc0); acc1 = fmaf(s7, bf16hi(u7), acc1);
            }
            for (; j + 4 <= mt; j += 4) {
                int   o0 = __shfl(ofs, j + 0), o1 = __shfl(ofs, j + 1);
                int   o2 = __shfl(ofs, j + 2), o3 = __shfl(ofs, j + 3);
                float s0 = __shfl(sc, j + 0), s1 = __shfl(sc, j + 1);
                float s2 = __shfl(sc, j + 2), s3 = __shfl(sc, j + 3);
                uint32_t u0 = hf[(size_t)(o0 + lane)];
                uint32_t u1 = hf[(size_t)(o1 + lane)];
                uint32_t u2 = hf[(size_t)(o2 + lane)];
                uint32_t u3 = hf[(size_t)(o3 + lane)];
                acc0 = fmaf(s0, bf16lo(u0), acc0); acc1 = fmaf(s0, bf16hi(u0), acc1);
                acc0 = fmaf(s1, bf16lo(u1), acc0); acc1 = fmaf(s1, bf16hi(u1), acc1);
                acc0 = fmaf(s2, bf16lo(u2), acc0); acc1 = fmaf(s2, bf16hi(u2), acc1);
                acc0 = fmaf(s3, bf16lo(u3), acc0); acc1 = fmaf(s3, bf16hi(u3), acc1);
            }
            for (; j < mt; ++j) {
                int oj = __shfl(ofs, j); float sj = __shfl(sc, j);
                uint32_t uj = hf[(size_t)(oj + lane)];
                acc0 = fmaf(sj, bf16lo(uj), acc0); acc1 = fmaf(sj, bf16hi(uj), acc1);
            }
        } else {
            // ultra-rare exact fallback (cf+cb > 64)
            for (int j = 0; j < cf; ++j) {
                int nb = adj_f[node * CAP + j];
                float dj = dvsf * dinv_f[nb];
                uint32_t u = hf[(size_t)nb * 64 + lane];
                acc0 = fmaf(dj, bf16lo(u), acc0); acc1 = fmaf(dj, bf16hi(u), acc1);
            }
            for (int j = 0; j < cb; ++j) {
                int nb = adj_b[node * CAP + j];
                float dj = dvsb * dinv_b[nb];
                uint32_t u = hf[(size_t)(nwords + nb * 64 + lane)];
                acc0 = fmaf(dj, bf16lo(u), acc0); acc1 = fmaf(dj, bf16hi(u), acc1);
            }
        }

        const float2 biasf = ((const float2*)bf)[lane];
        const float2 biasb = ((const float2*)bb)[lane];
        float v0 = acc0 + biasf.x + biasb.x;
        float v1 = acc1 + biasf.y + biasb.y;
        ((float2*)out)[(size_t)node * 64 + lane] =
            make_float2(fmaxf(v0, 0.0f), fmaxf(v1, 0.0f));
        return;
    }

    // ---- fixup blocks: exact recompute of overflowed rows ----
    int nov = *ovcnt; if (nov > OVMAX) nov = OVMAX;
    if (nov == 0) return;
    __shared__ int lst[4096];
    __shared__ int lcnt;
    const int tid = threadIdx.x;
    for (int i = bid - gnode; i < nov; i += 8) {
        int code = ovlist[i];
        int node = code >> 1;               // (node<<1)|dir encoding
        float acc0 = 0.f, acc1 = 0.f;
        for (int d2 = 0; d2 < 2; ++d2) {
            const int* key = d2 ? src : dst;
            const int* val = d2 ? dst : src;
            const float* dinv = d2 ? dinv_b : dinv_f;
            int base = d2 ? nwords : 0;
            float dvs = dinv[node];
            float s0 = 0.f, s1 = 0.f;
            if (tid < 64) {
                uint32_t u = hf[(size_t)(base + node * 64 + tid)];
                s0 = dvs * bf16lo(u); s1 = dvs * bf16hi(u);
            }
            for (int start = 0; start < ne; start += 4096) {
                if (tid == 0) lcnt = 0;
                __syncthreads();
                int end = min(start + 4096, ne);
                for (int e2 = start + tid; e2 < end; e2 += BLK)
                    if (key[e2] == node) { int q = atomicAdd(&lcnt, 1); lst[q] = val[e2]; }
                __syncthreads();
                int mm = lcnt;
                if (tid < 64) {
                    for (int j = 0; j < mm; ++j) {
                        int nb = lst[j];
                        float dv = dinv[nb];
                        uint32_t u = hf[(size_t)(base + nb * 64 + tid)];
                        s0 = fmaf(dv, bf16lo(u), s0);
                        s1 = fmaf(dv, bf16hi(u), s1);
                    }
                }
                __syncthreads();
            }
            if (tid < 64) { acc0 += dvs * s0; acc1 += dvs * s1; }
        }
        if (tid < 64) {
            float2 biasf = ((const float2*)bf)[tid];
            float2 biasb = ((const float2*)bb)[tid];
            float v0 = acc0 + biasf.x + biasb.x;
            float v1 = acc1 + biasf.y + biasb.y;
            ((float2*)out)[(size_t)node * 64 + tid] =
                make_float2(fmaxf(v0, 0.0f), fmaxf(v1, 0.0f));
        }
        __syncthreads();
    }
}

// ============================================================ launcher =====
extern "C" void kernel_launch(void* const* d_in, const int* in_sizes, int n_in,
                              void* d_out, int out_size, void* d_ws, size_t ws_size,
                              hipStream_t stream) {
    const float* x  = (const float*)d_in[0];
    const int*   ei = (const int*)d_in[1];
    const float* Wf = (const float*)d_in[2];
    const float* bf = (const float*)d_in[3];
    const float* Wb = (const float*)d_in[4];
    const float* bb = (const float*)d_in[5];

    const int n  = in_sizes[0] / 128;   // 50000
    const int ne = in_sizes[1] / 2;     // 625000
    const int* src = ei;
    const int* dst = ei + ne;
    float* out = (float*)d_out;

    const int nbins = (n + BINNODES - 1) >> BINSHIFT;   // 196 (must be <= 256)

    // workspace layout (16B-aligned; n, ne multiples of 4)
    // h_f and h_b contiguous (gather addresses h_b as h_f + nwords dwords).
    // pair_* and adj_* OVERLAY: per-bin pair segment (BINCAP*4 B) is byte-
    // identical to the bin's adj segment (BINNODES*CAP*2 B); k_build reads
    // pairs then dumps buckets in place.
    char* w = (char*)d_ws;
    unsigned short* h_f = (unsigned short*)w;   w += (size_t)n * 128 * 2;
    unsigned short* h_b = (unsigned short*)w;   w += (size_t)n * 128 * 2;
    uint32_t* pair_f = (uint32_t*)w;            w += (size_t)nbins * BINCAP * 4;
    uint32_t* pair_b = (uint32_t*)w;            w += (size_t)nbins * BINCAP * 4;
    float* dinv_f = (float*)w;                  w += (size_t)n * 4;
    float* dinv_b = (float*)w;                  w += (size_t)n * 4;
    unsigned short* WTf = (unsigned short*)w;   w += 128 * 128 * 2;
    unsigned short* WTb = (unsigned short*)w;   w += 128 * 128 * 2;
    int* cnt_f = (int*)w;                       w += (size_t)n * 4;
    int* cnt_b = (int*)w;                       w += (size_t)n * 4;
    int* gcnt_f = (int*)w;                      w += (size_t)nbins * 4;
    int* gcnt_b = (int*)w;                      w += (size_t)nbins * 4;
    int* ovcnt = (int*)w;                       w += 8 * 4;
    int* ovlist = (int*)w;                      w += OVMAX * 4;

    unsigned short* adj_f = (unsigned short*)pair_f;
    unsigned short* adj_b = (unsigned short*)pair_b;

    const int gbin  = (ne + EPB - 1) / EPB;             // 306 binning blocks
    const int gg    = (n + 15) / 16;                    // 3125 gemm blocks
    const int gnode = (n + 3) / 4;                      // 12500

    k_prep<<<9, BLK, 0, stream>>>(Wf, Wb, WTf, WTb, gcnt_f, 2 * nbins + 8);

    k_bin_gemm<<<gbin + gg, BLK, 0, stream>>>(src, dst, ne,
                                              pair_f, pair_b, gcnt_f, gcnt_b,
                                              ovcnt, ovlist,
                                              x, WTf, WTb, h_f, h_b,
                                              n, nbins, gbin);

    k_build<<<2 * nbins, BLK, 0, stream>>>(pair_f, pair_b, gcnt_f, gcnt_b,
                                           adj_f, adj_b, cnt_f, cnt_b,
                                           dinv_f, dinv_b, ovcnt, ovlist,
                                           n, nbins);

    k_gatherX<<<gnode + 8, BLK, 0, stream>>>(cnt_f, adj_f, cnt_b, adj_b,
                                             dinv_f, dinv_b,
                                             (const uint32_t*)h_f,
                                             (const uint32_t*)h_b,
                                             bf, bb, out, n, gnode, n * 64,
                                             ovcnt, ovlist, src, dst, ne);
}